// Round 4
// baseline (37.018 us; speedup 1.0000x reference)
//
#include <hip/hip_runtime.h>
#include <math.h>

// EigenMatrixGenerator: N=40 grid, state S=4800.
// Analytic collapse: A = Re(P diag(L) P^H), P diagonal-block structured =>
//   A[0,0](i) = lam1 + 2*Re(lam2)                  (= d1)
//   A[1,1]=A[1,2]=A[2,1]=A[2,2](i) = 2*|v2|^2*Re(lam2)  (= d2)
//   all other blocks are Re(z - conj(z)) = 0.
// W = (A - 0.97 I)/0.03. Outputs: A, W (23.04M f32 each), c_pos, k (1600 each).
//
// Pure HBM-write-bound (184.3 MB). This version makes the bulk loop
// instruction-identical to rocclr fillBuffer: each block owns a contiguous
// 5632-float4 chunk, zero-fills it with an unrolled pure-store loop, then
// (after __syncthreads) 24 designated threads patch the <=8 special float4s
// that fall inside the chunk (specials are at p = region*SS4 + r*1200 + col/4).

constexpr int       GN    = 40;
constexpr int       G     = GN * GN;               // 1600
constexpr int       S     = 3 * G;                 // 4800
constexpr long long SS    = (long long)S * S;      // 23,040,000
constexpr unsigned  ROW4  = S / 4;                 // 1200 float4 per row
constexpr unsigned  SS4   = (unsigned)(SS / 4);    // 5,760,000 float4 per matrix
constexpr unsigned  REGION = 2 * SS4;              // 11,520,000 float4 (A+W)
constexpr unsigned  TOT4  = REGION + (2 * G) / 4;  // 11,520,800
constexpr unsigned  NB    = 2048;
constexpr unsigned  IT    = 22;                    // ceil(REGION / (NB*256))
constexpr unsigned  CHUNK = IT * 256;              // 5632 float4 = 88 KiB

__device__ __forceinline__ float softplus_f(float x) {
    return fmaxf(x, 0.0f) + log1pf(expf(-fabsf(x)));
}

__global__ __launch_bounds__(256) void eigen_chunk_kernel(
        const float* __restrict__ c,
        const float* __restrict__ k,
        const float* __restrict__ kp,
        float* __restrict__ out) {
    const unsigned bid = blockIdx.x, tid = threadIdx.x;
    const unsigned lo  = bid * CHUNK;
    float4* __restrict__ out4 = (float4*)out;
    const float4 z = make_float4(0.f, 0.f, 0.f, 0.f);

    // ---- phase 1: pure zero-fill of this block's chunk (fill-kernel shape) ----
    if (lo + CHUNK <= REGION) {
        float4* p = out4 + lo + tid;
#pragma unroll
        for (unsigned it = 0; it < IT; ++it) p[it * 256u] = z;
    } else {
        for (unsigned idx = lo + tid; idx < REGION; idx += 256u) out4[idx] = z;
    }

    // tail outputs: c_pos (1600 f32) then k passthrough (1600 f32)
    if (bid == NB - 1) {
        for (unsigned t = tid; t < 2u * G; t += 256u)
            out[2 * SS + t] = (t < (unsigned)G) ? softplus_f(c[t]) : k[t - G];
    }

    __syncthreads();   // order patch stores after fill stores (same L2)

    // ---- phase 2: patch the special float4s inside [lo, hi) ----
    if (lo >= REGION) return;
    const unsigned hi = (lo + CHUNK < REGION) ? lo + CHUNK : REGION;

    // candidates: region(2: A,W) x rowslot(6) x spec(2) = 24
    if (tid < 24) {
        unsigned region = tid / 12;            // 0 = A, 1 = W
        unsigned slot   = (tid % 12) / 2;      // 0..5
        unsigned spec   = tid & 1;             // 0..1
        unsigned off    = region * SS4;

        unsigned ilo = lo > off ? lo : off;
        unsigned ihi = hi < off + SS4 ? hi : off + SS4;
        if (ilo < ihi) {
            unsigned r    = (ilo - off) / ROW4 + slot;
            unsigned rmax = (ihi - 1 - off) / ROW4;
            if (r <= rmax && r < (unsigned)S) {
                unsigned b = r / (unsigned)G;
                unsigned g = r - b * (unsigned)G;
                bool valid = (b != 0) || (spec == 0);
                if (valid) {
                    unsigned col = (b == 0) ? g
                                 : (spec == 0 ? (unsigned)G + g : 2u * G + g);
                    unsigned p_abs = off + r * ROW4 + (col >> 2);
                    if (p_abs >= lo && p_abs < hi) {
                        float c_pos = softplus_f(c[g]);
                        float k_x   = softplus_f(k[g]);
                        float kp_p  = softplus_f(kp[g]);

                        const float xi = 1.57079632679489662f;  // f32(pi/2)
                        float okx  = 1.0f + k_x;
                        float okp  = 1.0f + kp_p;
                        float lam1 = 1.0f / okx;
                        float rp   = 0.5f * (1.0f / okp + lam1);     // Re(lam2)
                        float im   = c_pos * xi / sqrtf(okp * okx);  // Im(lam2)
                        float ar   = rp - lam1 + 1e-6f;
                        float bx   = lam1 * xi;
                        float v2sq = bx * bx / (ar * ar + im * im);

                        float d1 = lam1 + 2.0f * rp;
                        float d2 = 2.0f * v2sq * rp;

                        const float INV_L = 1.0f / 0.03f;
                        const float OML   = 0.97f;

                        float base = (b == 0) ? d1 : d2;
                        bool  diag = (b == 0) || (b == 1 && spec == 0)
                                               || (b == 2 && spec == 1);
                        float val  = region ? (diag ? (base - OML) * INV_L
                                                    : base * INV_L)
                                            : base;

                        float4 v = z;
                        (&v.x)[col & 3] = val;
                        out4[p_abs] = v;
                    }
                }
            }
        }
    }
}

extern "C" void kernel_launch(void* const* d_in, const int* in_sizes, int n_in,
                              void* d_out, int out_size, void* d_ws, size_t ws_size,
                              hipStream_t stream) {
    const float* c  = (const float*)d_in[0];
    const float* k  = (const float*)d_in[1];
    const float* kp = (const float*)d_in[2];
    float* out = (float*)d_out;

    eigen_chunk_kernel<<<NB, 256, 0, stream>>>(c, k, kp, out);
}